// Round 1
// baseline (324.804 us; speedup 1.0000x reference)
//
#include <hip/hip_runtime.h>
#include <math.h>

typedef float vf4 __attribute__((ext_vector_type(4)));

constexpr int T = 8192;
constexpr int D = 128;
constexpr int N = 32;
constexpr int L = 64;            // chunk length
constexpr int LOG2L = 6;         // log2(L)
constexpr int K = T / L;         // 128 chunks
constexpr int S = N * D;         // 4096 state elements
constexpr int S4 = S / 4;        // 1024 float4 states
constexpr int D4 = D / 4;        // 32
constexpr int OSTRIDE4 = (2 * N * D) / 4;  // 2048 float4 per output time-row

// ---------------------------------------------------------------------------
// k1: per (chunk k, state s4): c_a[k][s4] = sum_i alpha * beta^(L-1-i) * x[kL+i]
// ---------------------------------------------------------------------------
__global__ __launch_bounds__(256) void k1_chunk_a(
    const vf4* __restrict__ x, const vf4* __restrict__ alpha,
    vf4* __restrict__ c_a)
{
    int gid = blockIdx.x * 256 + threadIdx.x;   // [0, K*S4)
    int k   = gid >> 10;                        // gid / S4
    int s4  = gid & (S4 - 1);
    int d4  = s4 & (D4 - 1);

    vf4 a = alpha[s4];
    vf4 b = 1.0f - a;
    vf4 c = {0.f, 0.f, 0.f, 0.f};
    const vf4* xp = x + (size_t)k * L * D4 + d4;
#pragma unroll 8
    for (int i = 0; i < L; ++i) {
        vf4 xv = xp[(size_t)i * D4];
        c = b * c + a * xv;
    }
    c_a[gid] = c;
}

// ---------------------------------------------------------------------------
// k2: per state, exclusive scan of chunk-start h_a; also writes hN_a tail.
// ---------------------------------------------------------------------------
__global__ __launch_bounds__(256) void k2_scan_a(
    const vf4* __restrict__ h_a0, const vf4* __restrict__ alpha,
    const vf4* __restrict__ c_a, vf4* __restrict__ h_a_start,
    float* __restrict__ out)
{
    int s4 = blockIdx.x * 256 + threadIdx.x;    // [0, S4)
    vf4 a = alpha[s4];
    vf4 b = 1.0f - a;
    vf4 bl = b;
#pragma unroll
    for (int i = 0; i < LOG2L; ++i) bl *= bl;   // beta^L

    vf4 h = h_a0[s4];
    for (int k = 0; k < K; ++k) {
        h_a_start[(size_t)k * S4 + s4] = h;
        h = bl * h + c_a[(size_t)k * S4 + s4];
    }
    // final state hN_a -> tail of out
    ((vf4*)(out + (size_t)T * 2 * N * D))[s4] = h;
}

// ---------------------------------------------------------------------------
// k3: per (chunk, state): walk chunk with true h_a start; write out_a rows;
//     accumulate chunk-local variance contribution c_v.
// ---------------------------------------------------------------------------
__global__ __launch_bounds__(256) void k3_walk_a(
    const vf4* __restrict__ x, const vf4* __restrict__ alpha,
    const vf4* __restrict__ h_a_start, vf4* __restrict__ c_v,
    vf4* __restrict__ out)
{
    int gid = blockIdx.x * 256 + threadIdx.x;
    int k   = gid >> 10;
    int s4  = gid & (S4 - 1);
    int n   = s4 >> 5;              // s4 / D4
    int d4  = s4 & (D4 - 1);

    vf4 a = alpha[s4];
    vf4 b = 1.0f - a;
    vf4 h = h_a_start[gid];
    vf4 v = {0.f, 0.f, 0.f, 0.f};
    const vf4* xp = x + (size_t)k * L * D4 + d4;
    vf4* op = out + (size_t)k * L * OSTRIDE4 + n * D4 + d4;
#pragma unroll 8
    for (int i = 0; i < L; ++i) {
        vf4 xv  = xp[(size_t)i * D4];
        vf4 dx  = xv - h;           // uses OLD h (matches reference)
        vf4 adx = a * dx;
        v = b * (v + adx * dx);
        h = h + adx;
        op[(size_t)i * OSTRIDE4] = h;
    }
    c_v[gid] = v;
}

// ---------------------------------------------------------------------------
// k4: per state, exclusive scan of chunk-start h_v; writes sqrt(hN_v) tail.
// ---------------------------------------------------------------------------
__global__ __launch_bounds__(256) void k4_scan_v(
    const vf4* __restrict__ h_sd0, const vf4* __restrict__ alpha,
    const vf4* __restrict__ c_v, vf4* __restrict__ h_v_start,
    float* __restrict__ out)
{
    int s4 = blockIdx.x * 256 + threadIdx.x;
    vf4 a = alpha[s4];
    vf4 b = 1.0f - a;
    vf4 bl = b;
#pragma unroll
    for (int i = 0; i < LOG2L; ++i) bl *= bl;

    vf4 sd = h_sd0[s4];
    vf4 h = sd * sd;
    for (int k = 0; k < K; ++k) {
        h_v_start[(size_t)k * S4 + s4] = h;
        h = bl * h + c_v[(size_t)k * S4 + s4];
    }
    vf4 r;
#pragma unroll
    for (int j = 0; j < 4; ++j) r[j] = sqrtf(h[j]);
    ((vf4*)(out + (size_t)T * 2 * N * D + S))[s4] = r;
}

// ---------------------------------------------------------------------------
// k5: per (chunk, state): re-walk chunk (recompute d identically), evolve h_v
//     from its true chunk-start, write sqrt(out_v) rows.
// ---------------------------------------------------------------------------
__global__ __launch_bounds__(256) void k5_walk_v(
    const vf4* __restrict__ x, const vf4* __restrict__ alpha,
    const vf4* __restrict__ h_a_start, const vf4* __restrict__ h_v_start,
    vf4* __restrict__ out)
{
    int gid = blockIdx.x * 256 + threadIdx.x;
    int k   = gid >> 10;
    int s4  = gid & (S4 - 1);
    int n   = s4 >> 5;
    int d4  = s4 & (D4 - 1);

    vf4 a = alpha[s4];
    vf4 b = 1.0f - a;
    vf4 h = h_a_start[gid];
    vf4 v = h_v_start[gid];
    const vf4* xp = x + (size_t)k * L * D4 + d4;
    vf4* op = out + (size_t)k * L * OSTRIDE4 + (N + n) * D4 + d4;
#pragma unroll 8
    for (int i = 0; i < L; ++i) {
        vf4 xv  = xp[(size_t)i * D4];
        vf4 dx  = xv - h;
        vf4 adx = a * dx;
        v = b * (v + adx * dx);
        h = h + adx;
        vf4 r;
#pragma unroll
        for (int j = 0; j < 4; ++j) r[j] = sqrtf(v[j]);
        op[(size_t)i * OSTRIDE4] = r;
    }
}

// ---------------------------------------------------------------------------
extern "C" void kernel_launch(void* const* d_in, const int* in_sizes, int n_in,
                              void* d_out, int out_size, void* d_ws, size_t ws_size,
                              hipStream_t stream) {
    const vf4* x     = (const vf4*)d_in[0];   // (T, D) fp32
    const vf4* h_a0  = (const vf4*)d_in[1];   // (N, D)
    const vf4* h_sd0 = (const vf4*)d_in[2];   // (N, D)
    const vf4* alpha = (const vf4*)d_in[3];   // (N, D)
    float* out = (float*)d_out;               // (T,2N,D) + hN_a (N,D) + hN_sd (N,D)
    float* ws  = (float*)d_ws;

    // workspace layout (floats): 4 arrays of K*S = 512K floats each (8 MB total)
    vf4* c_a       = (vf4*)(ws + 0 * (size_t)K * S);
    vf4* h_a_start = (vf4*)(ws + 1 * (size_t)K * S);
    vf4* c_v       = (vf4*)(ws + 2 * (size_t)K * S);
    vf4* h_v_start = (vf4*)(ws + 3 * (size_t)K * S);

    dim3 big(K * S4 / 256);   // 512 blocks
    dim3 small(S4 / 256);     // 4 blocks
    dim3 blk(256);

    k1_chunk_a<<<big,   blk, 0, stream>>>(x, alpha, c_a);
    k2_scan_a <<<small, blk, 0, stream>>>(h_a0, alpha, c_a, h_a_start, out);
    k3_walk_a <<<big,   blk, 0, stream>>>(x, alpha, h_a_start, c_v, (vf4*)out);
    k4_scan_v <<<small, blk, 0, stream>>>(h_sd0, alpha, c_v, h_v_start, out);
    k5_walk_v <<<big,   blk, 0, stream>>>(x, alpha, h_a_start, h_v_start, (vf4*)out);
}